// Round 2
// baseline (2325.483 us; speedup 1.0000x reference)
//
#include <hip/hip_runtime.h>
#include <math.h>

__device__ __forceinline__ float softsign(float v) {
    float d = 1.0f + fabsf(v);
    return v * __builtin_amdgcn_rcpf(d);
}

__device__ __forceinline__ void load_row6(const float* __restrict__ row, int x0, float r[6]) {
    // row points at x=0 of the (b,z,y) row; x0 is a multiple of 4 in [0,60]
    const float4 v = *(const float4*)(row + x0);
    r[0] = row[x0 == 0 ? 0 : x0 - 1];
    r[1] = v.x; r[2] = v.y; r[3] = v.z; r[4] = v.w;
    r[5] = row[x0 == 60 ? 63 : x0 + 4];
}

__device__ __forceinline__ int clamp63(int v) {
    return v < 0 ? 0 : (v > 63 ? 63 : v);
}

// -------- first layer: 2 input channels (preop, intraop) -> 1 channel --------
__global__ __launch_bounds__(256) void conv_first(const float* __restrict__ in0,
                                                  const float* __restrict__ in1,
                                                  float* __restrict__ out,
                                                  const float* __restrict__ w,   // (1,2,3,3,3) = 54
                                                  const float* __restrict__ bias) {
    int tid = blockIdx.x * 256 + threadIdx.x;
    int xq = (tid & 15) << 2;
    int y  = (tid >> 4) & 63;
    int z0 = ((tid >> 10) & 15) << 2;
    int b  = tid >> 14;
    const float* base0 = in0 + (size_t)b * 262144;
    const float* base1 = in1 + (size_t)b * 262144;

    float acc[4][4];
    #pragma unroll
    for (int i = 0; i < 4; ++i)
        #pragma unroll
        for (int j = 0; j < 4; ++j) acc[i][j] = 0.0f;

    #pragma unroll
    for (int zi = 0; zi < 6; ++zi) {
        int zin = clamp63(z0 + zi - 1);
        const float* p0 = base0 + zin * 4096;
        const float* p1 = base1 + zin * 4096;
        #pragma unroll
        for (int dy = 0; dy < 3; ++dy) {
            int yin = clamp63(y + dy - 1);
            float r0[6], r1[6];
            load_row6(p0 + yin * 64, xq, r0);
            load_row6(p1 + yin * 64, xq, r1);
            #pragma unroll
            for (int dz = 0; dz < 3; ++dz) {
                int zo = zi - dz;
                if (zo >= 0 && zo < 4) {
                    #pragma unroll
                    for (int dx = 0; dx < 3; ++dx) {
                        float w0v = w[dz * 9 + dy * 3 + dx];
                        float w1v = w[27 + dz * 9 + dy * 3 + dx];
                        #pragma unroll
                        for (int xx = 0; xx < 4; ++xx) {
                            acc[zo][xx] = fmaf(w0v, r0[xx + dx], acc[zo][xx]);
                            acc[zo][xx] = fmaf(w1v, r1[xx + dx], acc[zo][xx]);
                        }
                    }
                }
            }
        }
    }
    float bv = *bias;
    float* obase = out + (size_t)b * 262144 + (size_t)z0 * 4096 + y * 64 + xq;
    #pragma unroll
    for (int zo = 0; zo < 4; ++zo) {
        float4 o;
        o.x = softsign(acc[zo][0] + bv);
        o.y = softsign(acc[zo][1] + bv);
        o.z = softsign(acc[zo][2] + bv);
        o.w = softsign(acc[zo][3] + bv);
        *(float4*)(obase + zo * 4096) = o;
    }
}

// -------- middle layers: 1 -> 1 channel, 2z x 4x per thread, rolling z-window --------
// 2048 blocks x 256 threads = 524288 threads = 8192 waves = 32 waves/CU (8/SIMD).
// Rolling 3-row x 2-stage window keeps live VGPRs low so (256,8) holds.
__global__ __launch_bounds__(256, 8) void conv_mid(const float* __restrict__ in,
                                                   float* __restrict__ out,
                                                   const float* __restrict__ w,   // 27
                                                   const float* __restrict__ bias) {
    int tid = blockIdx.x * 256 + threadIdx.x;
    int xq = (tid & 15) << 2;
    int y  = (tid >> 4) & 63;
    int z0 = ((tid >> 10) & 31) << 1;
    int b  = tid >> 15;
    const float* base = in + (size_t)b * 262144;

    int yy[3];
    yy[0] = (y == 0) ? 0 : y - 1;
    yy[1] = y;
    yy[2] = (y == 63) ? 63 : y + 1;

    float acc[2][4];
    #pragma unroll
    for (int i = 0; i < 2; ++i)
        #pragma unroll
        for (int j = 0; j < 4; ++j) acc[i][j] = 0.0f;

    // preload plane for zi=0 (zin = clamp(z0-1))
    float cur[3][6];
    {
        const float* plane = base + (size_t)((z0 == 0) ? 0 : z0 - 1) * 4096;
        #pragma unroll
        for (int dy = 0; dy < 3; ++dy)
            load_row6(plane + yy[dy] * 64, xq, cur[dy]);
    }

    #pragma unroll
    for (int zi = 0; zi < 4; ++zi) {
        float nxt[3][6];
        if (zi < 3) {
            // plane for zi+1: zin = z0 + zi  (clamped high)
            int zn = z0 + zi;
            zn = zn > 63 ? 63 : zn;
            const float* plane = base + (size_t)zn * 4096;
            #pragma unroll
            for (int dy = 0; dy < 3; ++dy)
                load_row6(plane + yy[dy] * 64, xq, nxt[dy]);
        }
        // compute contributions of plane zi to outputs zo = zi - dz
        #pragma unroll
        for (int dz = 0; dz < 3; ++dz) {
            int zo = zi - dz;
            if (zo >= 0 && zo < 2) {
                #pragma unroll
                for (int dy = 0; dy < 3; ++dy) {
                    #pragma unroll
                    for (int dx = 0; dx < 3; ++dx) {
                        float wv = w[dz * 9 + dy * 3 + dx];
                        #pragma unroll
                        for (int xx = 0; xx < 4; ++xx)
                            acc[zo][xx] = fmaf(wv, cur[dy][xx + dx], acc[zo][xx]);
                    }
                }
            }
        }
        if (zi < 3) {
            #pragma unroll
            for (int dy = 0; dy < 3; ++dy)
                #pragma unroll
                for (int k = 0; k < 6; ++k)
                    cur[dy][k] = nxt[dy][k];
        }
    }

    float bv = *bias;
    float* obase = out + (size_t)b * 262144 + (size_t)z0 * 4096 + y * 64 + xq;
    #pragma unroll
    for (int zo = 0; zo < 2; ++zo) {
        float4 o;
        o.x = softsign(acc[zo][0] + bv);
        o.y = softsign(acc[zo][1] + bv);
        o.z = softsign(acc[zo][2] + bv);
        o.w = softsign(acc[zo][3] + bv);
        *(float4*)(obase + zo * 4096) = o;
    }
}

// -------- last layer: 1 -> 3 channels + strided downsample outputs --------
__global__ __launch_bounds__(256) void conv_last(const float* __restrict__ in,
                                                 float* __restrict__ out,
                                                 const float* __restrict__ w,    // (3,1,3,3,3) = 81
                                                 const float* __restrict__ bias) { // 3
    int tid = blockIdx.x * 256 + threadIdx.x;
    int xq = (tid & 15) << 2;
    int y  = (tid >> 4) & 63;
    int z0 = ((tid >> 10) & 15) << 2;
    int b  = tid >> 14;
    const float* base = in + (size_t)b * 262144;

    float acc[4][3][4];
    #pragma unroll
    for (int i = 0; i < 4; ++i)
        #pragma unroll
        for (int c = 0; c < 3; ++c)
            #pragma unroll
            for (int j = 0; j < 4; ++j) acc[i][c][j] = 0.0f;

    #pragma unroll
    for (int zi = 0; zi < 6; ++zi) {
        int zin = clamp63(z0 + zi - 1);
        const float* plane = base + zin * 4096;
        #pragma unroll
        for (int dy = 0; dy < 3; ++dy) {
            int yin = clamp63(y + dy - 1);
            float r[6];
            load_row6(plane + yin * 64, xq, r);
            #pragma unroll
            for (int dz = 0; dz < 3; ++dz) {
                int zo = zi - dz;
                if (zo >= 0 && zo < 4) {
                    #pragma unroll
                    for (int c = 0; c < 3; ++c) {
                        #pragma unroll
                        for (int dx = 0; dx < 3; ++dx) {
                            float wv = w[c * 27 + dz * 9 + dy * 3 + dx];
                            #pragma unroll
                            for (int xx = 0; xx < 4; ++xx)
                                acc[zo][c][xx] = fmaf(wv, r[xx + dx], acc[zo][c][xx]);
                        }
                    }
                }
            }
        }
    }

    float* r64 = out;
    float* r32 = out + 12582912;
    float* r16 = r32 + 1572864;
    float* r8  = r16 + 196608;

    float vals[4][3][4];
    #pragma unroll
    for (int zo = 0; zo < 4; ++zo)
        #pragma unroll
        for (int c = 0; c < 3; ++c) {
            float bv = bias[c];
            #pragma unroll
            for (int xx = 0; xx < 4; ++xx)
                vals[zo][c][xx] = softsign(acc[zo][c][xx] + bv);
        }

    // res64
    #pragma unroll
    for (int c = 0; c < 3; ++c) {
        float* cb = r64 + ((size_t)b * 3 + c) * 262144 + (size_t)z0 * 4096 + y * 64 + xq;
        #pragma unroll
        for (int zo = 0; zo < 4; ++zo) {
            float4 o;
            o.x = vals[zo][c][0]; o.y = vals[zo][c][1];
            o.z = vals[zo][c][2]; o.w = vals[zo][c][3];
            *(float4*)(cb + zo * 4096) = o;
        }
    }
    // res32: even z,y,x
    if ((y & 1) == 0) {
        #pragma unroll
        for (int c = 0; c < 3; ++c) {
            size_t cb = ((size_t)b * 3 + c) * 32768 + (size_t)(y >> 1) * 32;
            #pragma unroll
            for (int zo = 0; zo < 4; zo += 2) {
                size_t zb = cb + (size_t)((z0 + zo) >> 1) * 1024;
                r32[zb + ((xq + 0) >> 1)] = vals[zo][c][0];
                r32[zb + ((xq + 2) >> 1)] = vals[zo][c][2];
            }
        }
    }
    // res16: multiples of 4 -> zo==0, xx==0
    if ((y & 3) == 0) {
        #pragma unroll
        for (int c = 0; c < 3; ++c) {
            r16[((size_t)b * 3 + c) * 4096 + (size_t)(z0 >> 2) * 256 + (y >> 2) * 16 + (xq >> 2)] =
                vals[0][c][0];
        }
    }
    // res8: multiples of 8
    if ((y & 7) == 0 && (z0 & 7) == 0 && (xq & 7) == 0) {
        #pragma unroll
        for (int c = 0; c < 3; ++c) {
            r8[((size_t)b * 3 + c) * 512 + (size_t)(z0 >> 3) * 64 + (y >> 3) * 8 + (xq >> 3)] =
                vals[0][c][0];
        }
    }
}

extern "C" void kernel_launch(void* const* d_in, const int* in_sizes, int n_in,
                              void* d_out, int out_size, void* d_ws, size_t ws_size,
                              hipStream_t stream) {
    const float* preop = (const float*)d_in[0];
    const float* intra = (const float*)d_in[1];
    const float* w0    = (const float*)d_in[2];
    const float* b0    = (const float*)d_in[3];
    const float* ws    = (const float*)d_in[4];
    const float* bs    = (const float*)d_in[5];
    const float* wX    = (const float*)d_in[6];
    const float* bX    = (const float*)d_in[7];
    float* out = (float*)d_out;

    // ping-pong: buf0 in scratch (16.8 MB), buf1 aliased into d_out (rewritten by conv_last)
    float* buf0 = (float*)d_ws;
    float* buf1 = out;

    conv_first<<<dim3(1024), dim3(256), 0, stream>>>(preop, intra, buf0, w0, b0);
    for (int i = 0; i < 100; ++i) {
        const float* src = (i & 1) ? buf1 : buf0;
        float* dst       = (i & 1) ? buf0 : buf1;
        conv_mid<<<dim3(2048), dim3(256), 0, stream>>>(src, dst, ws + i * 27, bs + i);
    }
    // i=99 (odd) wrote buf0 -> final layer reads buf0, writes the real outputs
    conv_last<<<dim3(1024), dim3(256), 0, stream>>>(buf0, out, wX, bX);
}

// Round 3
// 1603.521 us; speedup vs baseline: 1.4502x; 1.4502x over previous
//
#include <hip/hip_runtime.h>
#include <math.h>

typedef float f4u __attribute__((ext_vector_type(4), aligned(4)));

__device__ __forceinline__ float softsign(float v) {
    float d = 1.0f + fabsf(v);
    return v * __builtin_amdgcn_rcpf(d);
}

__device__ __forceinline__ void load_row6(const float* __restrict__ row, int x0, float r[6]) {
    const float4 v = *(const float4*)(row + x0);
    r[0] = row[x0 == 0 ? 0 : x0 - 1];
    r[1] = v.x; r[2] = v.y; r[3] = v.z; r[4] = v.w;
    r[5] = row[x0 == 60 ? 63 : x0 + 4];
}

__device__ __forceinline__ int clamp63(int v) {
    return v < 0 ? 0 : (v > 63 ? 63 : v);
}

// -------- first layer: 2 input channels (preop, intraop) -> 1 channel --------
__global__ __launch_bounds__(256) void conv_first(const float* __restrict__ in0,
                                                  const float* __restrict__ in1,
                                                  float* __restrict__ out,
                                                  const float* __restrict__ w,   // 54
                                                  const float* __restrict__ bias) {
    int tid = blockIdx.x * 256 + threadIdx.x;
    int xq = (tid & 15) << 2;
    int y  = (tid >> 4) & 63;
    int z0 = ((tid >> 10) & 15) << 2;
    int b  = tid >> 14;
    const float* base0 = in0 + (size_t)b * 262144;
    const float* base1 = in1 + (size_t)b * 262144;

    float acc[4][4];
    #pragma unroll
    for (int i = 0; i < 4; ++i)
        #pragma unroll
        for (int j = 0; j < 4; ++j) acc[i][j] = 0.0f;

    #pragma unroll
    for (int zi = 0; zi < 6; ++zi) {
        int zin = clamp63(z0 + zi - 1);
        const float* p0 = base0 + zin * 4096;
        const float* p1 = base1 + zin * 4096;
        #pragma unroll
        for (int dy = 0; dy < 3; ++dy) {
            int yin = clamp63(y + dy - 1);
            float r0[6], r1[6];
            load_row6(p0 + yin * 64, xq, r0);
            load_row6(p1 + yin * 64, xq, r1);
            #pragma unroll
            for (int dz = 0; dz < 3; ++dz) {
                int zo = zi - dz;
                if (zo >= 0 && zo < 4) {
                    #pragma unroll
                    for (int dx = 0; dx < 3; ++dx) {
                        float w0v = w[dz * 9 + dy * 3 + dx];
                        float w1v = w[27 + dz * 9 + dy * 3 + dx];
                        #pragma unroll
                        for (int xx = 0; xx < 4; ++xx) {
                            acc[zo][xx] = fmaf(w0v, r0[xx + dx], acc[zo][xx]);
                            acc[zo][xx] = fmaf(w1v, r1[xx + dx], acc[zo][xx]);
                        }
                    }
                }
            }
        }
    }
    float bv = *bias;
    float* obase = out + (size_t)b * 262144 + (size_t)z0 * 4096 + y * 64 + xq;
    #pragma unroll
    for (int zo = 0; zo < 4; ++zo) {
        float4 o;
        o.x = softsign(acc[zo][0] + bv);
        o.y = softsign(acc[zo][1] + bv);
        o.z = softsign(acc[zo][2] + bv);
        o.w = softsign(acc[zo][3] + bv);
        *(float4*)(obase + zo * 4096) = o;
    }
}

// -------- middle layers: LDS-staged, 1 -> 1 channel, block computes 64x16y4z --------
// LDS tile: 6 planes x 18 rows x stride 68 floats, layout idx = x+1
// (idx0 = clamped x=-1, idx1..64 = x0..63, idx65 = clamped x=64). 29.4 KB.
// Compute window per row: ds_read_b128 @ idx xq (r0..r3) + ds_read_b64 @ idx xq+4 (r4,r5).
#define LPLANE 1224   // 18*68
#define LROW   68

__global__ __launch_bounds__(256) void conv_mid(const float* __restrict__ in,
                                                float* __restrict__ out,
                                                const float* __restrict__ w,   // 27
                                                const float* __restrict__ bias) {
    __shared__ float lds[6 * LPLANE];

    int blk = blockIdx.x;
    int y0  = (blk & 3) << 4;          // 0,16,32,48
    int z0  = ((blk >> 2) & 15) << 2;  // 0..60
    int b   = blk >> 6;                // 0..15
    int t   = threadIdx.x;
    int l   = t & 15;        // lane-within-group: x chunk
    int g   = t >> 4;        // group: row selector

    const float* base = in + (size_t)b * 262144;

    // ---- stage 108 rows (6 z-planes x 18 y-rows) into LDS ----
    #pragma unroll
    for (int p = 0; p < 7; ++p) {
        int row_id = p * 16 + g;
        if (row_id < 108) {
            int zi = row_id / 18;
            int ry = row_id - zi * 18;
            int gz = clamp63(z0 + zi - 1);
            int gy = clamp63(y0 + ry - 1);
            const float* grow = base + gz * 4096 + gy * 64;
            float* lrow = &lds[zi * LPLANE + ry * LROW];
            if (l == 0) {
                float4 v = *(const float4*)grow;             // x0..x3 (16B aligned)
                float4 o; o.x = v.x; o.y = v.x; o.z = v.y; o.w = v.z;  // x-1(clamp),x0,x1,x2
                *(float4*)lrow = o;
            } else {
                f4u v = *(const f4u*)(grow + 4 * l - 1);     // x(4l-1)..x(4l+2)
                *(float4*)(lrow + 4 * l) = (float4){v.x, v.y, v.z, v.w};
            }
            if (l == 15) {
                float t63 = grow[63];
                *(float2*)(lrow + 64) = (float2){t63, t63};  // x63, x64(clamp)
            }
        }
    }
    __syncthreads();

    // ---- compute 4z x 1y x 4x per thread from LDS ----
    int xq = l << 2;
    int ly = g;              // 0..15; LDS rows ly..ly+2 are y-1,y,y+1

    float acc[4][4];
    #pragma unroll
    for (int i = 0; i < 4; ++i)
        #pragma unroll
        for (int j = 0; j < 4; ++j) acc[i][j] = 0.0f;

    #pragma unroll
    for (int zi = 0; zi < 6; ++zi) {
        #pragma unroll
        for (int dy = 0; dy < 3; ++dy) {
            const float* lrow = &lds[zi * LPLANE + (ly + dy) * LROW];
            const float4 v  = *(const float4*)(lrow + xq);
            const float2 v2 = *(const float2*)(lrow + xq + 4);
            float r[6];
            r[0] = v.x; r[1] = v.y; r[2] = v.z; r[3] = v.w; r[4] = v2.x; r[5] = v2.y;
            #pragma unroll
            for (int dz = 0; dz < 3; ++dz) {
                int zo = zi - dz;
                if (zo >= 0 && zo < 4) {
                    #pragma unroll
                    for (int dx = 0; dx < 3; ++dx) {
                        float wv = w[dz * 9 + dy * 3 + dx];
                        #pragma unroll
                        for (int xx = 0; xx < 4; ++xx)
                            acc[zo][xx] = fmaf(wv, r[xx + dx], acc[zo][xx]);
                    }
                }
            }
        }
    }

    float bv = *bias;
    int y = y0 + ly;
    float* obase = out + (size_t)b * 262144 + (size_t)z0 * 4096 + y * 64 + xq;
    #pragma unroll
    for (int zo = 0; zo < 4; ++zo) {
        float4 o;
        o.x = softsign(acc[zo][0] + bv);
        o.y = softsign(acc[zo][1] + bv);
        o.z = softsign(acc[zo][2] + bv);
        o.w = softsign(acc[zo][3] + bv);
        *(float4*)(obase + zo * 4096) = o;
    }
}

// -------- last layer: 1 -> 3 channels + strided downsample outputs --------
__global__ __launch_bounds__(256) void conv_last(const float* __restrict__ in,
                                                 float* __restrict__ out,
                                                 const float* __restrict__ w,    // 81
                                                 const float* __restrict__ bias) { // 3
    int tid = blockIdx.x * 256 + threadIdx.x;
    int xq = (tid & 15) << 2;
    int y  = (tid >> 4) & 63;
    int z0 = ((tid >> 10) & 15) << 2;
    int b  = tid >> 14;
    const float* base = in + (size_t)b * 262144;

    float acc[4][3][4];
    #pragma unroll
    for (int i = 0; i < 4; ++i)
        #pragma unroll
        for (int c = 0; c < 3; ++c)
            #pragma unroll
            for (int j = 0; j < 4; ++j) acc[i][c][j] = 0.0f;

    #pragma unroll
    for (int zi = 0; zi < 6; ++zi) {
        int zin = clamp63(z0 + zi - 1);
        const float* plane = base + zin * 4096;
        #pragma unroll
        for (int dy = 0; dy < 3; ++dy) {
            int yin = clamp63(y + dy - 1);
            float r[6];
            load_row6(plane + yin * 64, xq, r);
            #pragma unroll
            for (int dz = 0; dz < 3; ++dz) {
                int zo = zi - dz;
                if (zo >= 0 && zo < 4) {
                    #pragma unroll
                    for (int c = 0; c < 3; ++c) {
                        #pragma unroll
                        for (int dx = 0; dx < 3; ++dx) {
                            float wv = w[c * 27 + dz * 9 + dy * 3 + dx];
                            #pragma unroll
                            for (int xx = 0; xx < 4; ++xx)
                                acc[zo][c][xx] = fmaf(wv, r[xx + dx], acc[zo][c][xx]);
                        }
                    }
                }
            }
        }
    }

    float* r64 = out;
    float* r32 = out + 12582912;
    float* r16 = r32 + 1572864;
    float* r8  = r16 + 196608;

    float vals[4][3][4];
    #pragma unroll
    for (int zo = 0; zo < 4; ++zo)
        #pragma unroll
        for (int c = 0; c < 3; ++c) {
            float bv = bias[c];
            #pragma unroll
            for (int xx = 0; xx < 4; ++xx)
                vals[zo][c][xx] = softsign(acc[zo][c][xx] + bv);
        }

    #pragma unroll
    for (int c = 0; c < 3; ++c) {
        float* cb = r64 + ((size_t)b * 3 + c) * 262144 + (size_t)z0 * 4096 + y * 64 + xq;
        #pragma unroll
        for (int zo = 0; zo < 4; ++zo) {
            float4 o;
            o.x = vals[zo][c][0]; o.y = vals[zo][c][1];
            o.z = vals[zo][c][2]; o.w = vals[zo][c][3];
            *(float4*)(cb + zo * 4096) = o;
        }
    }
    if ((y & 1) == 0) {
        #pragma unroll
        for (int c = 0; c < 3; ++c) {
            size_t cb = ((size_t)b * 3 + c) * 32768 + (size_t)(y >> 1) * 32;
            #pragma unroll
            for (int zo = 0; zo < 4; zo += 2) {
                size_t zb = cb + (size_t)((z0 + zo) >> 1) * 1024;
                r32[zb + ((xq + 0) >> 1)] = vals[zo][c][0];
                r32[zb + ((xq + 2) >> 1)] = vals[zo][c][2];
            }
        }
    }
    if ((y & 3) == 0) {
        #pragma unroll
        for (int c = 0; c < 3; ++c) {
            r16[((size_t)b * 3 + c) * 4096 + (size_t)(z0 >> 2) * 256 + (y >> 2) * 16 + (xq >> 2)] =
                vals[0][c][0];
        }
    }
    if ((y & 7) == 0 && (z0 & 7) == 0 && (xq & 7) == 0) {
        #pragma unroll
        for (int c = 0; c < 3; ++c) {
            r8[((size_t)b * 3 + c) * 512 + (size_t)(z0 >> 3) * 64 + (y >> 3) * 8 + (xq >> 3)] =
                vals[0][c][0];
        }
    }
}

extern "C" void kernel_launch(void* const* d_in, const int* in_sizes, int n_in,
                              void* d_out, int out_size, void* d_ws, size_t ws_size,
                              hipStream_t stream) {
    const float* preop = (const float*)d_in[0];
    const float* intra = (const float*)d_in[1];
    const float* w0    = (const float*)d_in[2];
    const float* b0    = (const float*)d_in[3];
    const float* ws    = (const float*)d_in[4];
    const float* bs    = (const float*)d_in[5];
    const float* wX    = (const float*)d_in[6];
    const float* bX    = (const float*)d_in[7];
    float* out = (float*)d_out;

    float* buf0 = (float*)d_ws;
    float* buf1 = out;

    conv_first<<<dim3(1024), dim3(256), 0, stream>>>(preop, intra, buf0, w0, b0);
    for (int i = 0; i < 100; ++i) {
        const float* src = (i & 1) ? buf1 : buf0;
        float* dst       = (i & 1) ? buf0 : buf1;
        conv_mid<<<dim3(1024), dim3(256), 0, stream>>>(src, dst, ws + i * 27, bs + i);
    }
    conv_last<<<dim3(1024), dim3(256), 0, stream>>>(buf0, out, wX, bX);
}

// Round 5
// 1573.066 us; speedup vs baseline: 1.4783x; 1.0194x over previous
//
#include <hip/hip_runtime.h>
#include <math.h>

typedef float f4u __attribute__((ext_vector_type(4), aligned(4)));
typedef float nfloat4 __attribute__((ext_vector_type(4), aligned(16)));

__device__ __forceinline__ float softsign(float v) {
    float d = 1.0f + fabsf(v);
    return v * __builtin_amdgcn_rcpf(d);
}

__device__ __forceinline__ void nt_store4(float* p, float a, float b, float c, float d) {
    nfloat4 v; v.x = a; v.y = b; v.z = c; v.w = d;
    __builtin_nontemporal_store(v, (nfloat4*)p);
}

__device__ __forceinline__ void load_row6(const float* __restrict__ row, int x0, float r[6]) {
    const float4 v = *(const float4*)(row + x0);
    r[0] = row[x0 == 0 ? 0 : x0 - 1];
    r[1] = v.x; r[2] = v.y; r[3] = v.z; r[4] = v.w;
    r[5] = row[x0 == 60 ? 63 : x0 + 4];
}

__device__ __forceinline__ int clamp63(int v) {
    return v < 0 ? 0 : (v > 63 ? 63 : v);
}

// -------- first layer: 2 input channels (preop, intraop) -> 1 channel --------
__global__ __launch_bounds__(256) void conv_first(const float* __restrict__ in0,
                                                  const float* __restrict__ in1,
                                                  float* __restrict__ out,
                                                  const float* __restrict__ w,   // 54
                                                  const float* __restrict__ bias) {
    int tid = blockIdx.x * 256 + threadIdx.x;
    int xq = (tid & 15) << 2;
    int y  = (tid >> 4) & 63;
    int z0 = ((tid >> 10) & 15) << 2;
    int b  = tid >> 14;
    const float* base0 = in0 + (size_t)b * 262144;
    const float* base1 = in1 + (size_t)b * 262144;

    float acc[4][4];
    #pragma unroll
    for (int i = 0; i < 4; ++i)
        #pragma unroll
        for (int j = 0; j < 4; ++j) acc[i][j] = 0.0f;

    #pragma unroll
    for (int zi = 0; zi < 6; ++zi) {
        int zin = clamp63(z0 + zi - 1);
        const float* p0 = base0 + zin * 4096;
        const float* p1 = base1 + zin * 4096;
        #pragma unroll
        for (int dy = 0; dy < 3; ++dy) {
            int yin = clamp63(y + dy - 1);
            float r0[6], r1[6];
            load_row6(p0 + yin * 64, xq, r0);
            load_row6(p1 + yin * 64, xq, r1);
            #pragma unroll
            for (int dz = 0; dz < 3; ++dz) {
                int zo = zi - dz;
                if (zo >= 0 && zo < 4) {
                    #pragma unroll
                    for (int dx = 0; dx < 3; ++dx) {
                        float w0v = w[dz * 9 + dy * 3 + dx];
                        float w1v = w[27 + dz * 9 + dy * 3 + dx];
                        #pragma unroll
                        for (int xx = 0; xx < 4; ++xx) {
                            acc[zo][xx] = fmaf(w0v, r0[xx + dx], acc[zo][xx]);
                            acc[zo][xx] = fmaf(w1v, r1[xx + dx], acc[zo][xx]);
                        }
                    }
                }
            }
        }
    }
    float bv = *bias;
    float* obase = out + (size_t)b * 262144 + (size_t)z0 * 4096 + y * 64 + xq;
    #pragma unroll
    for (int zo = 0; zo < 4; ++zo) {
        nt_store4(obase + zo * 4096,
                  softsign(acc[zo][0] + bv), softsign(acc[zo][1] + bv),
                  softsign(acc[zo][2] + bv), softsign(acc[zo][3] + bv));
    }
}

// -------- middle layers: LDS-staged, 1 -> 1 channel, block computes 64x16y4z --------
#define LPLANE 1224   // 18*68
#define LROW   68

__global__ __launch_bounds__(256) void conv_mid(const float* __restrict__ in,
                                                float* __restrict__ out,
                                                const float* __restrict__ w,   // 27
                                                const float* __restrict__ bias) {
    __shared__ float lds[6 * LPLANE];

    int blk = blockIdx.x;
    int y0  = (blk & 3) << 4;
    int z0  = ((blk >> 2) & 15) << 2;
    int b   = blk >> 6;
    int t   = threadIdx.x;
    int l   = t & 15;
    int g   = t >> 4;

    const float* base = in + (size_t)b * 262144;

    #pragma unroll
    for (int p = 0; p < 7; ++p) {
        int row_id = p * 16 + g;
        if (row_id < 108) {
            int zi = row_id / 18;
            int ry = row_id - zi * 18;
            int gz = clamp63(z0 + zi - 1);
            int gy = clamp63(y0 + ry - 1);
            const float* grow = base + gz * 4096 + gy * 64;
            float* lrow = &lds[zi * LPLANE + ry * LROW];
            if (l == 0) {
                float4 v = *(const float4*)grow;
                float4 o; o.x = v.x; o.y = v.x; o.z = v.y; o.w = v.z;
                *(float4*)lrow = o;
            } else {
                f4u v = *(const f4u*)(grow + 4 * l - 1);
                *(float4*)(lrow + 4 * l) = (float4){v.x, v.y, v.z, v.w};
            }
            if (l == 15) {
                float t63 = grow[63];
                *(float2*)(lrow + 64) = (float2){t63, t63};
            }
        }
    }
    __syncthreads();

    int xq = l << 2;
    int ly = g;

    float acc[4][4];
    #pragma unroll
    for (int i = 0; i < 4; ++i)
        #pragma unroll
        for (int j = 0; j < 4; ++j) acc[i][j] = 0.0f;

    #pragma unroll
    for (int zi = 0; zi < 6; ++zi) {
        #pragma unroll
        for (int dy = 0; dy < 3; ++dy) {
            const float* lrow = &lds[zi * LPLANE + (ly + dy) * LROW];
            const float4 v  = *(const float4*)(lrow + xq);
            const float2 v2 = *(const float2*)(lrow + xq + 4);
            float r[6];
            r[0] = v.x; r[1] = v.y; r[2] = v.z; r[3] = v.w; r[4] = v2.x; r[5] = v2.y;
            #pragma unroll
            for (int dz = 0; dz < 3; ++dz) {
                int zo = zi - dz;
                if (zo >= 0 && zo < 4) {
                    #pragma unroll
                    for (int dx = 0; dx < 3; ++dx) {
                        float wv = w[dz * 9 + dy * 3 + dx];
                        #pragma unroll
                        for (int xx = 0; xx < 4; ++xx)
                            acc[zo][xx] = fmaf(wv, r[xx + dx], acc[zo][xx]);
                    }
                }
            }
        }
    }

    float bv = *bias;
    int y = y0 + ly;
    float* obase = out + (size_t)b * 262144 + (size_t)z0 * 4096 + y * 64 + xq;
    #pragma unroll
    for (int zo = 0; zo < 4; ++zo) {
        nt_store4(obase + zo * 4096,
                  softsign(acc[zo][0] + bv), softsign(acc[zo][1] + bv),
                  softsign(acc[zo][2] + bv), softsign(acc[zo][3] + bv));
    }
}

// -------- last layer: 1 -> 3 channels + strided downsample outputs --------
__global__ __launch_bounds__(256) void conv_last(const float* __restrict__ in,
                                                 float* __restrict__ out,
                                                 const float* __restrict__ w,    // 81
                                                 const float* __restrict__ bias) { // 3
    int tid = blockIdx.x * 256 + threadIdx.x;
    int xq = (tid & 15) << 2;
    int y  = (tid >> 4) & 63;
    int z0 = ((tid >> 10) & 15) << 2;
    int b  = tid >> 14;
    const float* base = in + (size_t)b * 262144;

    float acc[4][3][4];
    #pragma unroll
    for (int i = 0; i < 4; ++i)
        #pragma unroll
        for (int c = 0; c < 3; ++c)
            #pragma unroll
            for (int j = 0; j < 4; ++j) acc[i][c][j] = 0.0f;

    #pragma unroll
    for (int zi = 0; zi < 6; ++zi) {
        int zin = clamp63(z0 + zi - 1);
        const float* plane = base + zin * 4096;
        #pragma unroll
        for (int dy = 0; dy < 3; ++dy) {
            int yin = clamp63(y + dy - 1);
            float r[6];
            load_row6(plane + yin * 64, xq, r);
            #pragma unroll
            for (int dz = 0; dz < 3; ++dz) {
                int zo = zi - dz;
                if (zo >= 0 && zo < 4) {
                    #pragma unroll
                    for (int c = 0; c < 3; ++c) {
                        #pragma unroll
                        for (int dx = 0; dx < 3; ++dx) {
                            float wv = w[c * 27 + dz * 9 + dy * 3 + dx];
                            #pragma unroll
                            for (int xx = 0; xx < 4; ++xx)
                                acc[zo][c][xx] = fmaf(wv, r[xx + dx], acc[zo][c][xx]);
                        }
                    }
                }
            }
        }
    }

    float* r64 = out;
    float* r32 = out + 12582912;
    float* r16 = r32 + 1572864;
    float* r8  = r16 + 196608;

    float vals[4][3][4];
    #pragma unroll
    for (int zo = 0; zo < 4; ++zo)
        #pragma unroll
        for (int c = 0; c < 3; ++c) {
            float bv = bias[c];
            #pragma unroll
            for (int xx = 0; xx < 4; ++xx)
                vals[zo][c][xx] = softsign(acc[zo][c][xx] + bv);
        }

    #pragma unroll
    for (int c = 0; c < 3; ++c) {
        float* cb = r64 + ((size_t)b * 3 + c) * 262144 + (size_t)z0 * 4096 + y * 64 + xq;
        #pragma unroll
        for (int zo = 0; zo < 4; ++zo) {
            nt_store4(cb + zo * 4096,
                      vals[zo][c][0], vals[zo][c][1], vals[zo][c][2], vals[zo][c][3]);
        }
    }
    if ((y & 1) == 0) {
        #pragma unroll
        for (int c = 0; c < 3; ++c) {
            size_t cb = ((size_t)b * 3 + c) * 32768 + (size_t)(y >> 1) * 32;
            #pragma unroll
            for (int zo = 0; zo < 4; zo += 2) {
                size_t zb = cb + (size_t)((z0 + zo) >> 1) * 1024;
                __builtin_nontemporal_store(vals[zo][c][0], r32 + zb + ((xq + 0) >> 1));
                __builtin_nontemporal_store(vals[zo][c][2], r32 + zb + ((xq + 2) >> 1));
            }
        }
    }
    if ((y & 3) == 0) {
        #pragma unroll
        for (int c = 0; c < 3; ++c) {
            __builtin_nontemporal_store(vals[0][c][0],
                r16 + ((size_t)b * 3 + c) * 4096 + (size_t)(z0 >> 2) * 256 + (y >> 2) * 16 + (xq >> 2));
        }
    }
    if ((y & 7) == 0 && (z0 & 7) == 0 && (xq & 7) == 0) {
        #pragma unroll
        for (int c = 0; c < 3; ++c) {
            __builtin_nontemporal_store(vals[0][c][0],
                r8 + ((size_t)b * 3 + c) * 512 + (size_t)(z0 >> 3) * 64 + (y >> 3) * 8 + (xq >> 3));
        }
    }
}

extern "C" void kernel_launch(void* const* d_in, const int* in_sizes, int n_in,
                              void* d_out, int out_size, void* d_ws, size_t ws_size,
                              hipStream_t stream) {
    const float* preop = (const float*)d_in[0];
    const float* intra = (const float*)d_in[1];
    const float* w0    = (const float*)d_in[2];
    const float* b0    = (const float*)d_in[3];
    const float* ws    = (const float*)d_in[4];
    const float* bs    = (const float*)d_in[5];
    const float* wX    = (const float*)d_in[6];
    const float* bX    = (const float*)d_in[7];
    float* out = (float*)d_out;

    float* buf0 = (float*)d_ws;
    float* buf1 = out;

    conv_first<<<dim3(1024), dim3(256), 0, stream>>>(preop, intra, buf0, w0, b0);
    for (int i = 0; i < 100; ++i) {
        const float* src = (i & 1) ? buf1 : buf0;
        float* dst       = (i & 1) ? buf0 : buf1;
        conv_mid<<<dim3(1024), dim3(256), 0, stream>>>(src, dst, ws + i * 27, bs + i);
    }
    conv_last<<<dim3(1024), dim3(256), 0, stream>>>(buf0, out, wX, bX);
}